// Round 8
// baseline (880.337 us; speedup 1.0000x reference)
//
#include <hip/hip_runtime.h>

#define NPTS   8192
#define NBATCH 16
#define NGROUP 512
#define GSIZE  32
#define BIGF   1e10f

typedef unsigned long long u64;

// DPP max on a packed u64 key: shift both 32-bit halves with the same ctrl,
// compare-select. CTRL must be an ICE. bound_ctrl=true injects key=0
// (val=0.0, enc-idx=0 i.e. idx 8191) which loses every comparison against a
// real candidate (distinct indices -> distinct keys, val>=0), so it's inert.
template <int CTRL>
__device__ __forceinline__ u64 dpp_max_u64(u64 k) {
    const unsigned lo  = (unsigned)k;
    const unsigned hi  = (unsigned)(k >> 32);
    const unsigned slo = (unsigned)__builtin_amdgcn_update_dpp(0, (int)lo, CTRL, 0xF, 0xF, true);
    const unsigned shi = (unsigned)__builtin_amdgcn_update_dpp(0, (int)hi, CTRL, 0xF, 0xF, true);
    const u64 s = ((u64)shi << 32) | slo;
    return s > k ? s : k;
}

__device__ __forceinline__ u64 umax64(u64 a, u64 b) { return a > b ? a : b; }

// ---------------------------------------------------------------------------
// Prepack: xyz of every point as float4 (one coalesced 16B load in knn).
// ---------------------------------------------------------------------------
__global__ __launch_bounds__(256) void prepack_kernel(const float* __restrict__ pc,
                                                      float4* __restrict__ ws4) {
    const int i = blockIdx.x * 256 + threadIdx.x;     // 0 .. 131071
    const float* s = pc + (size_t)i * 6;
    ws4[i] = make_float4(s[0], s[1], s[2], 0.0f);
}

// ---------------------------------------------------------------------------
// Kernel 1: farthest point sampling. One block per batch, 1024 threads
// (16 waves, 4/SIMD — round-8 experiment: double latency hiding on the serial
// path, halve the per-wave dependent chain; per-CU VALU work unchanged).
// 8 points/thread in registers; coords in LDS float4 for the broadcast read.
// Scalar verified-exact math (f32x2 scalarized anyway — reverted).
// Wave argmax: packed u64 key (bits(val)<<13)|(8191-idx) reduced in the DPP
// butterfly; lane 63 holds the wave winner. Max over keys == (max value,
// lowest index) — identical selection to jnp.argmax.
// Cross-wave: 16 u64 keys in LDS read as 8x ulonglong2 (b128), tree max.
// ---------------------------------------------------------------------------
__global__ __launch_bounds__(1024) void fps_kernel(const float* __restrict__ pc,
                                                   int* __restrict__ rep) {
    const int b    = blockIdx.x;
    const int t    = threadIdx.x;
    const int lane = t & 63;
    const int w    = t >> 6;

    __shared__ float4 sp[NPTS];                      // 128 KB
    __shared__ __align__(16) u64 keys[2][16];
    __shared__ int lrep[NGROUP];                     // 2 KB

    const float* base = pc + (size_t)b * NPTS * 6;

    float px[8], py[8], pz[8], dmin[8];
#pragma unroll
    for (int j = 0; j < 8; ++j) {
        const int p = t * 8 + j;
        const float x = base[p * 6 + 0];
        const float y = base[p * 6 + 1];
        const float z = base[p * 6 + 2];
        px[j] = x; py[j] = y; pz[j] = z;
        sp[p] = make_float4(x, y, z, 0.0f);
        dmin[j] = BIGF;
    }
    __syncthreads();

    int last = 0;
    for (int k = 0; k < NGROUP; ++k) {
        if (t == 0) lrep[k] = last;                  // LDS, not global

        const float4 L = sp[last];                   // one ds_read_b128, broadcast

        float bv = -1.0f;
        int   bi = 0;
#pragma unroll
        for (int j = 0; j < 8; ++j) {
            const float dx = __fsub_rn(px[j], L.x);
            const float dy = __fsub_rn(py[j], L.y);
            const float dz = __fsub_rn(pz[j], L.z);
            // ((dx^2 + dy^2) + dz^2), no FMA -> matches numpy fp32 (verified)
            const float d = __fadd_rn(__fadd_rn(__fmul_rn(dx, dx),
                                                __fmul_rn(dy, dy)),
                                      __fmul_rn(dz, dz));
            const float dm = fminf(dmin[j], d);
            dmin[j] = dm;
            if (dm > bv) { bv = dm; bi = t * 8 + j; }    // strict > keeps lowest idx
        }
        if (k == NGROUP - 1) break;

        // pack once, reduce packed key via DPP (no shuffles, no ballot)
        u64 key = ((u64)__float_as_uint(bv) << 13) | (unsigned)(8191 - bi);
        key = dpp_max_u64<0x111>(key);   // row_shr:1
        key = dpp_max_u64<0x112>(key);   // row_shr:2
        key = dpp_max_u64<0x114>(key);   // row_shr:4
        key = dpp_max_u64<0x118>(key);   // row_shr:8
        key = dpp_max_u64<0x142>(key);   // row_bcast:15
        key = dpp_max_u64<0x143>(key);   // row_bcast:31 -> lane 63 = wave max

        const int buf = k & 1;                       // parity dbuf -> 1 barrier/iter
        if (lane == 63) keys[buf][w] = key;
        __syncthreads();

        const ulonglong2* kp = (const ulonglong2*)keys[buf];   // 8x ds_read_b128
        u64 m0 = umax64(kp[0].x, kp[0].y);
        u64 m1 = umax64(kp[1].x, kp[1].y);
        u64 m2 = umax64(kp[2].x, kp[2].y);
        u64 m3 = umax64(kp[3].x, kp[3].y);
        u64 m4 = umax64(kp[4].x, kp[4].y);
        u64 m5 = umax64(kp[5].x, kp[5].y);
        u64 m6 = umax64(kp[6].x, kp[6].y);
        u64 m7 = umax64(kp[7].x, kp[7].y);
        const u64 best = umax64(umax64(umax64(m0, m1), umax64(m2, m3)),
                                umax64(umax64(m4, m5), umax64(m6, m7)));
        last = 8191 - (int)(best & 0x1FFFull);
    }

    __syncthreads();                                 // lrep visibility
    if (t < NGROUP)                                  // one coalesced write-out
        rep[b * NGROUP + t] = lrep[t];
}

// ---------------------------------------------------------------------------
// Kernel 2: 32-NN per sampled center + gathers. One wave per query,
// 256-thread blocks. Scan reads prepacked float4 (coalesced 16B, L2-resident).
// d2 in fp64 difference form (bit-robust true ranking; passed rounds 3/5/6/7).
// Top-32 as lane-distributed sorted list, lower-index tie-break.
// tau broadcast skipped on iterations with no accepts (wave-uniform guard).
// ---------------------------------------------------------------------------
__global__ __launch_bounds__(256) void knn_kernel(const float* __restrict__ pc,
                                                  const float4* __restrict__ ws4,
                                                  const int* __restrict__ rep,
                                                  float* __restrict__ out) {
    const int tid  = threadIdx.x;
    const int lane = tid & 63;
    const int w    = tid >> 6;
    const int q    = blockIdx.x * 4 + w;       // 0 .. 8191
    const int b    = q >> 9;

    const float*  base  = pc  + (size_t)b * NPTS * 6;
    const float4* base4 = ws4 + ((size_t)b << 13);
    const int     r     = rep[q];

    const float4 Q = base4[r];
    const float qxf = Q.x, qyf = Q.y, qzf = Q.z;
    const double qx = (double)qxf, qy = (double)qyf, qz = (double)qzf;

    const double DINF = __longlong_as_double(0x7ff0000000000000LL);
    double vd = DINF;  int vi = 0x7fffffff;    // distributed sorted list entry
    double taud = DINF; int taui = 0x7fffffff; // current 32nd element (lane 31)

    for (int i = 0; i < NPTS / 64; ++i) {
        const int p = i * 64 + lane;
        const float4 T = base4[p];             // coalesced 16B
        const double dx = qx - (double)T.x;
        const double dy = qy - (double)T.y;
        const double dz = qz - (double)T.z;
        const double d2 = dx * dx + dy * dy + dz * dz;   // no cancellation

        const bool acc = (d2 < taud) || (d2 == taud && p < taui);
        const unsigned long long mask0 = __ballot(acc);
        unsigned long long mask = mask0;
        while (mask) {
            const int l = __ffsll(mask) - 1;
            mask &= mask - 1;
            const double xd = __shfl(d2, l);
            const int    xi = __shfl(p, l);
            const double pd = __shfl_up(vd, 1);
            const int    pi = __shfl_up(vi, 1);
            const bool ltp = (lane > 0) && ((xd < pd) || (xd == pd && xi < pi));
            const bool ltc = (xd < vd) || (xd == vd && xi < vi);
            const double nvd = ltp ? pd : (ltc ? xd : vd);
            const int    nvi = ltp ? pi : (ltc ? xi : vi);
            vd = nvd; vi = nvi;
        }
        if (mask0) {                           // wave-uniform: tau unchanged if no accept
            taud = __shfl(vd, 31);
            taui = __shfl(vi, 31);
        }
    }

    // ---- outputs ----
    const size_t NBH = (size_t)NBATCH * NGROUP * GSIZE * 6;   // neighborhood elems
    const size_t CEN = (size_t)NBATCH * NGROUP * 6;           // center elems

    if (lane == 0) {
#pragma unroll
        for (int c = 0; c < 6; ++c)
            out[NBH + (size_t)q * 6 + c] = base[r * 6 + c];
    }
    if (lane < GSIZE) {
        const int n = vi;                      // lane-sorted: position == lane
        out[NBH + CEN + (size_t)q * GSIZE + lane] = (float)n;

        const float* np_ = base + (size_t)n * 6;
        const size_t o = ((size_t)q * GSIZE + lane) * 6;
        out[o + 0] = __fsub_rn(np_[0], qxf);
        out[o + 1] = __fsub_rn(np_[1], qyf);
        out[o + 2] = __fsub_rn(np_[2], qzf);
        out[o + 3] = np_[3];
        out[o + 4] = np_[4];
        out[o + 5] = np_[5];
    }
}

extern "C" void kernel_launch(void* const* d_in, const int* in_sizes, int n_in,
                              void* d_out, int out_size, void* d_ws, size_t ws_size,
                              hipStream_t stream) {
    const float* pc  = (const float*)d_in[0];
    float*       out = (float*)d_out;
    int*         rep = (int*)d_ws;                              // 32 KB
    float4*      ws4 = (float4*)((char*)d_ws + 32 * 1024);      // 2 MB

    prepack_kernel<<<NBATCH * NPTS / 256, 256, 0, stream>>>(pc, ws4);
    fps_kernel<<<NBATCH, 1024, 0, stream>>>(pc, rep);
    knn_kernel<<<NBATCH * NGROUP / 4, 256, 0, stream>>>(pc, ws4, rep, out);
}